// Round 7
// baseline (6074.122 us; speedup 1.0000x reference)
//
#include <hip/hip_runtime.h>
#include <hip/hip_bf16.h>

#define B_   256
#define T_   64
#define OBS_ 1024
#define ACT_ 6
#define STO_ 32
#define HID_ 1024
#define DET_ 1024

using bf16 = __bf16;
typedef __attribute__((ext_vector_type(8))) __bf16 bf16x8;
typedef __attribute__((ext_vector_type(4))) float f32x4;

__device__ __forceinline__ f32x4 MF(bf16x8 a, bf16x8 b, f32x4 c) {
  return __builtin_amdgcn_mfma_f32_16x16x32_bf16(a, b, c, 0, 0, 0);
}

// ---------------- fused weight conversion (single launch) ----------------
struct CvtArgs {
  const float *in_w2, *gru_wih, *gru_whh, *pr_w1, *pr_w2, *po_w1, *po_w2;
  const float *pr_mw, *pr_sw, *po_mw, *po_sw;
  bf16 *w_in2b, *w_wihb, *w_whhb, *w_pr1b, *w_pr2b, *w_po1hb, *w_po1ob, *w_po2b, *w_headb;
};

__global__ void k_cvtall(CvtArgs a) {
  const int row = blockIdx.x;            // 12416 rows total
  const float* src; bf16* dst;
  if      (row < 1024)  { src = a.in_w2   + (size_t)row * 1024;          dst = a.w_in2b  + (size_t)row * 1024; }
  else if (row < 4096)  { int r = row - 1024;  src = a.gru_wih + (size_t)r * 1024; dst = a.w_wihb + (size_t)r * 1024; }
  else if (row < 7168)  { int r = row - 4096;  src = a.gru_whh + (size_t)r * 1024; dst = a.w_whhb + (size_t)r * 1024; }
  else if (row < 8192)  { int r = row - 7168;  src = a.pr_w1   + (size_t)r * 1024; dst = a.w_pr1b + (size_t)r * 1024; }
  else if (row < 9216)  { int r = row - 8192;  src = a.pr_w2   + (size_t)r * 1024; dst = a.w_pr2b + (size_t)r * 1024; }
  else if (row < 10240) { int r = row - 9216;  src = a.po_w1   + (size_t)r * 2048; dst = a.w_po1hb + (size_t)r * 1024; }
  else if (row < 11264) { int r = row - 10240; src = a.po_w1   + (size_t)r * 2048 + 1024; dst = a.w_po1ob + (size_t)r * 1024; }
  else if (row < 12288) { int r = row - 11264; src = a.po_w2   + (size_t)r * 1024; dst = a.w_po2b + (size_t)r * 1024; }
  else {
    int r = row - 12288;                 // 0..127 head rows
    const float* hs[4] = { a.pr_mw, a.pr_sw, a.po_mw, a.po_sw };
    src = hs[r >> 5] + (size_t)(r & 31) * 1024;
    dst = a.w_headb + (size_t)r * 1024;
  }
  const int c = threadIdx.x * 4;
  float4 f = *(const float4*)(src + c);
  dst[c] = (bf16)f.x; dst[c + 1] = (bf16)f.y; dst[c + 2] = (bf16)f.z; dst[c + 3] = (bf16)f.w;
}

// ---------------- state init ----------------
__global__ void k_init(const float* __restrict__ in_b1, bf16* __restrict__ x1b,
                       bf16* __restrict__ hb, float* __restrict__ hf) {
  const int i = blockIdx.x * 256 + threadIdx.x;      // < 262144
  x1b[i] = (bf16)fmaxf(in_b1[i & 1023], 0.f);        // z0=0, a0=0
  hb[i] = (bf16)0.f;
  hf[i] = 0.f;
}

// ---------------- batched obs-part of po1 (runs once, 4096 blocks) ----------------
__global__ __launch_bounds__(256) void k_qbatch(
    const float* __restrict__ obs, const bf16* __restrict__ w,
    const float* __restrict__ bias, float* __restrict__ out) {
  const int tid = threadIdx.x, lane = tid & 63, wv = tid >> 6;
  const int l15 = lane & 15, kg = lane >> 4, kq = kg * 8, rq = kg * 4;
  const int m0 = (blockIdx.x & 255) * 64 + wv * 16;
  const int n0 = (blockIdx.x >> 8) * 64;
  f32x4 c0{0.f,0.f,0.f,0.f}, c1 = c0, c2 = c0, c3 = c0;
  const float* __restrict__ ap = obs + (size_t)(m0 + l15) * 1024 + kq;
  const bf16* __restrict__ wp = w + (size_t)(n0 + l15) * 1024 + kq;
  #pragma unroll 2
  for (int k = 0; k < 1024; k += 32) {
    float4 f0 = *(const float4*)(ap + k);
    float4 f1 = *(const float4*)(ap + k + 4);
    bf16x8 af;
    af[0] = (bf16)f0.x; af[1] = (bf16)f0.y; af[2] = (bf16)f0.z; af[3] = (bf16)f0.w;
    af[4] = (bf16)f1.x; af[5] = (bf16)f1.y; af[6] = (bf16)f1.z; af[7] = (bf16)f1.w;
    c0 = MF(af, *(const bf16x8*)(wp + k            ), c0);
    c1 = MF(af, *(const bf16x8*)(wp + 16 * 1024 + k), c1);
    c2 = MF(af, *(const bf16x8*)(wp + 32 * 1024 + k), c2);
    c3 = MF(af, *(const bf16x8*)(wp + 48 * 1024 + k), c3);
  }
  f32x4 cc[4] = {c0, c1, c2, c3};
  #pragma unroll
  for (int t2 = 0; t2 < 4; ++t2) {
    const int n = n0 + t2 * 16 + l15;
    const float bv = bias[n];
    #pragma unroll
    for (int r = 0; r < 4; ++r)
      out[(size_t)(m0 + rq + r) * 1024 + n] = cc[t2][r] + bv;
  }
}

// ---------------- split-K multi-GEMM, 512 thr / 8 waves ----------------
// MR rows per tile x 64 n-cols. MR=64: 4 msub x 2 kw (KSEG=512, 16 iters).
// MR=32: 2 msub x 4 kw (KSEG=256, 8 iters). LDS reduce, kw=0 wave does epilogue.
struct GB {
  const bf16* A;      // [256, lda]
  const bf16* W;      // [N, 1024] row-major
  const float* bias;  // [n] or null
  const float* acc;   // f32 addend, row stride accStride, or null
  bf16* outB;         // or null
  float* outF;        // or null
  int N, lda, relu, accStride;
};

template<int MR>
__global__ __launch_bounds__(512, 2) void k_mg2(GB g0, GB g1, int s1) {
  constexpr int NMT  = 256 / MR;          // tiles along m
  constexpr int MSUB = MR / 16;           // m-subtiles per block (4 or 2)
  constexpr int RED  = 8 / MSUB;          // K-split factor (2 or 4)
  constexpr int KSEG = 1024 / RED;        // 512 or 256
  GB g; int tile;
  if ((int)blockIdx.x < s1) { g = g0; tile = blockIdx.x; }
  else                      { g = g1; tile = blockIdx.x - s1; }
  __shared__ float sh[(RED - 1) * MSUB * 1056];
  const int tid = threadIdx.x, lane = tid & 63, wv = tid >> 6;
  const int msub = wv & (MSUB - 1), kw = wv / MSUB;
  const int l15 = lane & 15, kg = lane >> 4, kq = kg * 8, rq = kg * 4;
  const int m0 = (tile % NMT) * MR + msub * 16;
  const int n0 = (tile / NMT) * 64;
  const int kb = kw * KSEG;

  f32x4 c0{0.f,0.f,0.f,0.f}, c1 = c0, c2 = c0, c3 = c0;
  const bf16* __restrict__ ap = g.A + (size_t)(m0 + l15) * g.lda + kb + kq;
  const bf16* __restrict__ wp = g.W + (size_t)(n0 + l15) * 1024 + kb + kq;
  #pragma unroll
  for (int k = 0; k < KSEG; k += 32) {
    bf16x8 af = *(const bf16x8*)(ap + k);
    c0 = MF(af, *(const bf16x8*)(wp + k            ), c0);
    c1 = MF(af, *(const bf16x8*)(wp + 16 * 1024 + k), c1);
    c2 = MF(af, *(const bf16x8*)(wp + 32 * 1024 + k), c2);
    c3 = MF(af, *(const bf16x8*)(wp + 48 * 1024 + k), c3);
  }
  f32x4 cc[4] = {c0, c1, c2, c3};
  if (kw) {
    float* s = sh + ((kw - 1) * MSUB + msub) * 1056;
    #pragma unroll
    for (int t2 = 0; t2 < 4; ++t2)
      #pragma unroll
      for (int r = 0; r < 4; ++r)
        s[(rq + r) * 66 + t2 * 16 + l15] = cc[t2][r];
  }
  __syncthreads();
  if (kw == 0) {
    #pragma unroll
    for (int t2 = 0; t2 < 4; ++t2) {
      const int n = n0 + t2 * 16 + l15;
      const float bv = g.bias ? g.bias[n] : 0.f;
      #pragma unroll
      for (int r = 0; r < 4; ++r) {
        const int row = m0 + rq + r;
        float v = cc[t2][r] + bv;
        #pragma unroll
        for (int s = 0; s < RED - 1; ++s)
          v += sh[(s * MSUB + msub) * 1056 + (rq + r) * 66 + t2 * 16 + l15];
        if (g.acc) v += g.acc[(size_t)row * g.accStride + n];
        if (g.relu) v = fmaxf(v, 0.f);
        if (g.outB) g.outB[(size_t)row * g.N + n] = (bf16)v;
        if (g.outF) g.outF[(size_t)row * g.N + n] = v;
      }
    }
  }
}

// ---------------- gi GEMM + GRU gates, 512 thr / 8 waves, 64-row tiles ----------------
// block (mt 0..3, cs 0..63): rows mt*64..+64, gate-cols cs*16..+16 of r/z/n chunks.
__global__ __launch_bounds__(512, 2) void k_gates3(
    const bf16* __restrict__ x2b, const bf16* __restrict__ wihb,
    const float* __restrict__ bih, const float* __restrict__ gh,
    float* __restrict__ hf, bf16* __restrict__ hb, float* __restrict__ feat, int t) {
  __shared__ float sh[4 * 816];          // 4 msub slots x (3 gates x 16 x 17)
  const int mt = blockIdx.x & 3, cs = blockIdx.x >> 2;
  const int tid = threadIdx.x, lane = tid & 63, wv = tid >> 6;
  const int msub = wv & 3, kw = wv >> 2;
  const int l15 = lane & 15, kg = lane >> 4, kq = kg * 8, rq = kg * 4;
  const int mrow = mt * 64 + msub * 16;

  f32x4 ar{0.f,0.f,0.f,0.f}, az = ar, an = ar;
  const bf16* __restrict__ ap = x2b + (size_t)(mrow + l15) * 1024 + kw * 512 + kq;
  const bf16* __restrict__ wr = wihb + (size_t)(cs * 16 + l15) * 1024 + kw * 512 + kq;
  const size_t GOFF = (size_t)1024 * 1024;
  #pragma unroll
  for (int k = 0; k < 512; k += 32) {
    bf16x8 af = *(const bf16x8*)(ap + k);
    ar = MF(af, *(const bf16x8*)(wr + k           ), ar);
    az = MF(af, *(const bf16x8*)(wr + GOFF + k    ), az);
    an = MF(af, *(const bf16x8*)(wr + 2 * GOFF + k), an);
  }
  if (kw) {
    float* s = sh + msub * 816;
    #pragma unroll
    for (int r = 0; r < 4; ++r) {
      s[(rq + r) * 17 + l15]       = ar[r];
      s[272 + (rq + r) * 17 + l15] = az[r];
      s[544 + (rq + r) * 17 + l15] = an[r];
    }
  }
  __syncthreads();
  if (kw == 0) {
    const int c = cs * 16 + l15;
    const float bir = bih[c], biz = bih[1024 + c], bin_ = bih[2048 + c];
    float* s = sh + msub * 816;
    #pragma unroll
    for (int r = 0; r < 4; ++r) {
      const float vr = ar[r] + s[(rq + r) * 17 + l15];
      const float vz = az[r] + s[272 + (rq + r) * 17 + l15];
      const float vn = an[r] + s[544 + (rq + r) * 17 + l15];
      const int m = mrow + rq + r;
      const float* ghp = gh + (size_t)m * 3072 + c;
      float rr = vr + bir + ghp[0];
      float zz = vz + biz + ghp[1024];
      const float hn = ghp[2048];
      rr = 1.f / (1.f + __expf(-rr));
      zz = 1.f / (1.f + __expf(-zz));
      const float nn = tanhf(vn + bin_ + rr * hn);
      const float h2 = (1.f - zz) * nn + zz * hf[(size_t)m * 1024 + c];
      hf[(size_t)m * 1024 + c] = h2;
      hb[(size_t)m * 1024 + c] = (bf16)h2;
      feat[((size_t)m * T_ + t) * 1056 + c] = h2;
    }
  }
}

// ---------------- heads + stats + z + feat_z + next x1 (16 blocks x 1024) ----------------
__global__ __launch_bounds__(1024, 1) void k_headfin2(
    const bf16* __restrict__ p2b, const bf16* __restrict__ q2b,
    const bf16* __restrict__ whead,            // [128,1024]: pr_m, pr_s, po_m, po_s
    const float* __restrict__ pr_mb, const float* __restrict__ pr_sb,
    const float* __restrict__ po_mb, const float* __restrict__ po_sb,
    const float* __restrict__ eps, const float* __restrict__ act,
    const float* __restrict__ in_w1, const float* __restrict__ in_b1,
    float* __restrict__ pm, float* __restrict__ ps,
    float* __restrict__ qm, float* __restrict__ qs,
    float* __restrict__ feat, bf16* __restrict__ x1b, int t) {
  __shared__ float sh[8 * 1056];        // 8 waves x 16 x 66
  __shared__ float zm[16][32], zs[16][32], zl[16][32], al[16][8];
  const int g = blockIdx.x, m0 = g * 16;
  const int tid = threadIdx.x, lane = tid & 63, w = tid >> 6;
  const int l15 = lane & 15, kg = lane >> 4, kq = kg * 8, rq = kg * 4;

  if (w < 8) {
    const int kw = w & 3, half = w >> 2;
    const bf16* __restrict__ A = half ? q2b : p2b;
    f32x4 c0{0.f,0.f,0.f,0.f}, c1 = c0, c2 = c0, c3 = c0;
    const bf16* __restrict__ ap = A + (size_t)(m0 + l15) * 1024 + kw * 256 + kq;
    const bf16* __restrict__ wp = whead + (size_t)(half * 64 + l15) * 1024 + kw * 256 + kq;
    #pragma unroll
    for (int k = 0; k < 256; k += 32) {
      bf16x8 af = *(const bf16x8*)(ap + k);
      c0 = MF(af, *(const bf16x8*)(wp + k            ), c0);
      c1 = MF(af, *(const bf16x8*)(wp + 16 * 1024 + k), c1);
      c2 = MF(af, *(const bf16x8*)(wp + 32 * 1024 + k), c2);
      c3 = MF(af, *(const bf16x8*)(wp + 48 * 1024 + k), c3);
    }
    f32x4 cc[4] = {c0, c1, c2, c3};
    float* s = sh + w * 1056;
    #pragma unroll
    for (int t2 = 0; t2 < 4; ++t2)
      #pragma unroll
      for (int r = 0; r < 4; ++r)
        s[(rq + r) * 66 + t2 * 16 + l15] = cc[t2][r];
  }
  if (tid >= 928 && tid < 1024) {       // 96 threads: load actions
    const int idx = tid - 928, r = idx / ACT_, k = idx - r * ACT_;
    al[r][k] = act[((size_t)(m0 + r) * T_ + t) * ACT_ + k];
  }
  __syncthreads();

  #pragma unroll
  for (int rep = 0; rep < 2; ++rep) {
    const int idx = rep * 1024 + tid;   // 0..2047 = 16 rows x 128 cols
    const int r = idx >> 7, c = idx & 127;
    const int base = (c < 64) ? 0 : 4, cl = c & 63;
    float v = sh[base * 1056 + r * 66 + cl] + sh[(base + 1) * 1056 + r * 66 + cl]
            + sh[(base + 2) * 1056 + r * 66 + cl] + sh[(base + 3) * 1056 + r * 66 + cl];
    const size_t ob = ((size_t)(m0 + r) * T_ + t) * STO_ + (c & 31);
    const int sel = c >> 5;
    if (sel == 0) {
      pm[ob] = v + pr_mb[c];
    } else if (sel == 1) {
      ps[ob] = __expf(fminf(fmaxf(v + pr_sb[c - 32], -5.f), 2.f));
    } else if (sel == 2) {
      const float x = v + po_mb[c - 64];
      qm[ob] = x; zm[r][c - 64] = x;
    } else {
      const float x = __expf(fminf(fmaxf(v + po_sb[c - 96], -5.f), 2.f));
      qs[ob] = x; zs[r][c - 96] = x;
    }
  }
  __syncthreads();
  if (tid < 512) {
    const int r = tid >> 5, j = tid & 31;
    const float z = zm[r][j] + zs[r][j] * eps[((size_t)(m0 + r) * T_ + t) * STO_ + j];
    zl[r][j] = z;
    feat[((size_t)(m0 + r) * T_ + t) * 1056 + 1024 + j] = z;
  }
  __syncthreads();

  // x1_{t+1}: each thread owns output col n=tid for all 16 rows; w1 row in regs.
  const int n = tid;
  float wv_[38];
  #pragma unroll
  for (int j = 0; j < 38; ++j) wv_[j] = in_w1[(size_t)n * 38 + j];
  const float bn = in_b1[n];
  #pragma unroll 2
  for (int r = 0; r < 16; ++r) {
    float a = bn;
    #pragma unroll
    for (int k = 0; k < STO_; ++k) a = fmaf(zl[r][k], wv_[k], a);
    #pragma unroll
    for (int k = 0; k < ACT_; ++k) a = fmaf(al[r][k], wv_[32 + k], a);
    x1b[(size_t)(m0 + r) * 1024 + n] = (bf16)fmaxf(a, 0.f);
  }
}

extern "C" void kernel_launch(void* const* d_in, const int* in_sizes, int n_in,
                              void* d_out, int out_size, void* d_ws, size_t ws_size,
                              hipStream_t stream) {
  (void)in_sizes; (void)n_in; (void)out_size; (void)ws_size;
  const float* obs      = (const float*)d_in[0];
  const float* actions  = (const float*)d_in[1];
  const float* eps_post = (const float*)d_in[3];   // eps_prior unused by the math
  const float* in_w1 = (const float*)d_in[4];
  const float* in_b1 = (const float*)d_in[5];
  const float* in_w2 = (const float*)d_in[6];
  const float* in_b2 = (const float*)d_in[7];
  const float* gru_wih = (const float*)d_in[8];
  const float* gru_whh = (const float*)d_in[9];
  const float* gru_bih = (const float*)d_in[10];
  const float* gru_bhh = (const float*)d_in[11];
  const float* pr_w1 = (const float*)d_in[12];
  const float* pr_b1 = (const float*)d_in[13];
  const float* pr_w2 = (const float*)d_in[14];
  const float* pr_b2 = (const float*)d_in[15];
  const float* pr_mw = (const float*)d_in[16];
  const float* pr_mb = (const float*)d_in[17];
  const float* pr_sw = (const float*)d_in[18];
  const float* pr_sb = (const float*)d_in[19];
  const float* po_w1 = (const float*)d_in[20];
  const float* po_b1 = (const float*)d_in[21];
  const float* po_w2 = (const float*)d_in[22];
  const float* po_b2 = (const float*)d_in[23];
  const float* po_mw = (const float*)d_in[24];
  const float* po_mb = (const float*)d_in[25];
  const float* po_sw = (const float*)d_in[26];
  const float* po_sb = (const float*)d_in[27];

  float* feat = (float*)d_out;
  float* pm = feat + (size_t)B_ * T_ * 1056;
  float* ps = pm + (size_t)B_ * T_ * STO_;
  float* qm = ps + (size_t)B_ * T_ * STO_;
  float* qs = qm + (size_t)B_ * T_ * STO_;

  char* wp_ = (char*)d_ws;
  auto carve = [&](size_t bytes) -> void* {
    void* r = (void*)wp_;
    wp_ += (bytes + 255) & ~(size_t)255;
    return r;
  };
  bf16* w_in2b  = (bf16*)carve((size_t)HID_ * HID_ * 2);
  bf16* w_wihb  = (bf16*)carve((size_t)3 * DET_ * HID_ * 2);
  bf16* w_whhb  = (bf16*)carve((size_t)3 * DET_ * DET_ * 2);
  bf16* w_pr1b  = (bf16*)carve((size_t)HID_ * DET_ * 2);
  bf16* w_pr2b  = (bf16*)carve((size_t)HID_ * HID_ * 2);
  bf16* w_po1hb = (bf16*)carve((size_t)HID_ * DET_ * 2);
  bf16* w_po1ob = (bf16*)carve((size_t)HID_ * OBS_ * 2);
  bf16* w_po2b  = (bf16*)carve((size_t)HID_ * HID_ * 2);
  bf16* w_headb = (bf16*)carve((size_t)128 * HID_ * 2);
  bf16* x1b  = (bf16*)carve((size_t)B_ * HID_ * 2);
  bf16* x2b  = (bf16*)carve((size_t)B_ * HID_ * 2);
  bf16* hb   = (bf16*)carve((size_t)B_ * DET_ * 2);
  bf16* p1b  = (bf16*)carve((size_t)B_ * HID_ * 2);
  bf16* q1b  = (bf16*)carve((size_t)B_ * HID_ * 2);
  bf16* p2b  = (bf16*)carve((size_t)B_ * HID_ * 2);
  bf16* q2b  = (bf16*)carve((size_t)B_ * HID_ * 2);
  float* hf    = (float*)carve((size_t)B_ * DET_ * 4);
  float* gh    = (float*)carve((size_t)B_ * 3 * DET_ * 4);
  float* q1acc = (float*)carve((size_t)B_ * T_ * HID_ * 4);   // 64 MB

  // ---- prologue ----
  CvtArgs ca = { in_w2, gru_wih, gru_whh, pr_w1, pr_w2, po_w1, po_w2,
                 pr_mw, pr_sw, po_mw, po_sw,
                 w_in2b, w_wihb, w_whhb, w_pr1b, w_pr2b, w_po1hb, w_po1ob, w_po2b, w_headb };
  k_cvtall<<<dim3(12416), dim3(256), 0, stream>>>(ca);
  k_init<<<dim3(1024), dim3(256), 0, stream>>>(in_b1, x1b, hb, hf);
  k_qbatch<<<dim3(4096), dim3(256), 0, stream>>>(obs, w_po1ob, po_b1, q1acc);

  for (int t = 0; t < T_; ++t) {
    // K1: x2 (64 tiles, MR=64) || gh (192 tiles) -> 256 blocks
    GB g_x2 = { x1b, w_in2b, in_b2,   nullptr, x2b, nullptr, 1024, 1024, 1, 0 };
    GB g_gh = { hb,  w_whhb, gru_bhh, nullptr, nullptr, gh, 3072, 1024, 0, 0 };
    k_mg2<64><<<dim3(256), dim3(512), 0, stream>>>(g_x2, g_gh, 64);

    // K2: gi + GRU gates -> h, feat_h (256 blocks)
    k_gates3<<<dim3(256), dim3(512), 0, stream>>>(x2b, w_wihb, gru_bih, gh, hf, hb, feat, t);

    // K3: pr1 (128 tiles, MR=32) || q1 (128) -> 256 blocks
    GB g_pr1 = { hb, w_pr1b,  pr_b1,   nullptr,           p1b, nullptr, 1024, 1024, 1, 0 };
    GB g_q1  = { hb, w_po1hb, nullptr, q1acc + t * 1024,  q1b, nullptr, 1024, 1024, 1, T_ * 1024 };
    k_mg2<32><<<dim3(256), dim3(512), 0, stream>>>(g_pr1, g_q1, 128);

    // K4: pr2 (128) || po2 (128) -> 256 blocks
    GB g_pr2 = { p1b, w_pr2b, pr_b2, nullptr, p2b, nullptr, 1024, 1024, 1, 0 };
    GB g_po2 = { q1b, w_po2b, po_b2, nullptr, q2b, nullptr, 1024, 1024, 1, 0 };
    k_mg2<32><<<dim3(256), dim3(512), 0, stream>>>(g_pr2, g_po2, 128);

    // K5: all heads + stats + z + feat_z + next x1
    k_headfin2<<<dim3(16), dim3(1024), 0, stream>>>(
        p2b, q2b, w_headb, pr_mb, pr_sb, po_mb, po_sb,
        eps_post, actions, in_w1, in_b1, pm, ps, qm, qs, feat, x1b, t);
  }
}